// Round 12
// baseline (1373.689 us; speedup 1.0000x reference)
//
#include <hip/hip_runtime.h>
#include <hip/hip_bf16.h>

#define N_NODES 50000
#define N_EDGES 800000
#define DIM 64
#define HID 128
#define NGRAPH 128
#define BN_EPS 1e-5f

typedef __attribute__((ext_vector_type(8))) short short8;
typedef __attribute__((ext_vector_type(4))) short short4v;
typedef __attribute__((ext_vector_type(4))) float f32x4;
typedef __attribute__((ext_vector_type(4))) int int4v;

__device__ __forceinline__ float sp_(float v) {
    // softplus via hardware v_exp_f32 / v_log_f32 (~1e-6 abs err, fine at bf16)
    return fmaxf(v, 0.f) + __logf(1.f + __expf(-fabsf(v)));
}
__device__ __forceinline__ short bfb(float f) {
    __hip_bfloat16 h = __float2bfloat16(f);
    return __builtin_bit_cast(short, h);
}
__device__ __forceinline__ float b2f(short s) {
    unsigned u = ((unsigned)(unsigned short)s) << 16;
    return __builtin_bit_cast(float, u);
}

// ---------------------------------------------------------------- embed
__global__ void k_embed(const int* __restrict__ az, const float* __restrict__ emb,
                        float* __restrict__ x, __hip_bfloat16* __restrict__ xb) {
    int idx = blockIdx.x * 256 + threadIdx.x;
    if (idx >= N_NODES * DIM) return;
    int n = idx >> 6;
    int d = idx & 63;
    float v = emb[az[n] * DIM + d];
    x[idx] = v;
    xb[idx] = __float2bfloat16(v);
}

// ---------------------------------------------------------------- weight prep:
// transpose f32 [K][N] (row-major) -> bf16 [N][K]; blockIdx.y = layer
__global__ void k_wprep(const float* __restrict__ src, short* __restrict__ dst,
                        int total, int nshift, int srcStride) {
    int l = blockIdx.y;
    int idx = blockIdx.x * 256 + threadIdx.x;
    if (idx >= total) return;
    int K = total >> nshift;
    int k = idx >> nshift;
    int n = idx & ((1 << nshift) - 1);
    dst[(size_t)l * total + n * K + k] = bfb(src[(size_t)l * srcStride + idx]);
}

// ---------------------------------------------------------------- counting sort by dst
__global__ void k_hist(const int* __restrict__ edst, int* __restrict__ deg) {
    int e = blockIdx.x * 256 + threadIdx.x;
    if (e < N_EDGES) atomicAdd(&deg[edst[e]], 1);
}

// single block, 1024 threads: exclusive prefix sum deg -> cursor
__global__ void k_scan(const int* __restrict__ deg, int* __restrict__ cursor) {
    __shared__ int wsum[16];
    __shared__ int carry;
    const int t = threadIdx.x, lane = t & 63, w = t >> 6;
    if (t == 0) carry = 0;
    __syncthreads();
    for (int base = 0; base < N_NODES; base += 1024) {
        int i = base + t;
        int v = (i < N_NODES) ? deg[i] : 0;
        int s = v;
#pragma unroll
        for (int off = 1; off < 64; off <<= 1) {
            int u = __shfl_up(s, off);
            if (lane >= off) s += u;
        }
        if (lane == 63) wsum[w] = s;
        __syncthreads();
        if (w == 0) {
            int ws = (lane < 16) ? wsum[lane] : 0;
#pragma unroll
            for (int off = 1; off < 16; off <<= 1) {
                int u = __shfl_up(ws, off);
                if (lane >= off) ws += u;
            }
            if (lane < 16) wsum[lane] = ws;
        }
        __syncthreads();
        int woff = (w == 0) ? 0 : wsum[w - 1];
        int excl = carry + woff + s - v;
        if (i < N_NODES) cursor[i] = excl;
        __syncthreads();
        if (t == 1023) carry += wsum[15];
        __syncthreads();
    }
}

// scatter into interleaved edge records {src, dst, attr_bits, 0}
__global__ void k_scatter(const int* __restrict__ esrc, const int* __restrict__ edst,
                          const float* __restrict__ eattr, int* __restrict__ cursor,
                          int4v* __restrict__ sedge) {
    int e = blockIdx.x * 256 + threadIdx.x;
    if (e >= N_EDGES) return;
    int d = edst[e];
    int pos = atomicAdd(&cursor[d], 1);
    int4v rec = {esrc[e], d, __builtin_bit_cast(int, eattr[e]), 0};
    sedge[pos] = rec;
}

// ---------------------------------------------------------------- graph bounds
__global__ void k_gbounds(const int* __restrict__ batch, int* __restrict__ gstart) {
    int g = threadIdx.x;
    if (g > NGRAPH) return;
    int lo = 0, hi = N_NODES;
    while (lo < hi) {
        int mid = (lo + hi) >> 1;
        if (batch[mid] < g) lo = mid + 1; else hi = mid;
    }
    gstart[g] = lo;
}

// ---------------------------------------------------------------- per-node A/B (layer 0):
// A[n] = x[n]@W1[0:64] + b1, B[n] = x[n]@W1[64:128]
// output xab[n][0:128]=A bf16, [128:256]=B bf16
__launch_bounds__(512, 2)
__global__ void k_ab(const __hip_bfloat16* __restrict__ xb,
                     const short* __restrict__ w1T, const float* __restrict__ b1,
                     short* __restrict__ xab) {
    __shared__ short xt[64 * 64];     // 8KB, rowbytes 128
    __shared__ short ot[64 * 256];    // 32KB, rowbytes 512
    const int t = threadIdx.x;
    const int wid = t >> 6, lane = t & 63, lrow = lane & 15, lk = lane >> 4;
    const int col = wid * 16 + lrow;
    const int n0 = blockIdx.x * 64;

    short8 wa[2], wb[2];
#pragma unroll
    for (int ks = 0; ks < 2; ks++) {
        wa[ks] = *(const short8*)((const char*)w1T + col * 256 + ks * 64 + lk * 16);
        wb[ks] = *(const short8*)((const char*)w1T + col * 256 + 128 + ks * 64 + lk * 16);
    }
    const float b1v = b1[col];

    {   // stage x tile
        int r = t >> 3, q = t & 7;
        int node = n0 + r;
        int4v v = {0, 0, 0, 0};
        if (node < N_NODES) v = *(const int4v*)(xb + (size_t)node * DIM + q * 8);
        *(int4v*)((char*)xt + r * 128 + ((q * 16) ^ ((r & 7) << 4))) = v;
    }
    __syncthreads();

    f32x4 aa[4], ab[4];
#pragma unroll
    for (int mi = 0; mi < 4; mi++) { aa[mi] = (f32x4){0.f,0.f,0.f,0.f}; ab[mi] = (f32x4){0.f,0.f,0.f,0.f}; }
#pragma unroll
    for (int ks = 0; ks < 2; ks++) {
        int kb = ks * 64 + lk * 16;
        short8 av[4];
#pragma unroll
        for (int mi = 0; mi < 4; mi++) {
            int row = mi * 16 + lrow;
            av[mi] = *(const short8*)((const char*)xt + row * 128 + (kb ^ ((row & 7) << 4)));
        }
#pragma unroll
        for (int mi = 0; mi < 4; mi++) {
            aa[mi] = __builtin_amdgcn_mfma_f32_16x16x32_bf16(av[mi], wa[ks], aa[mi], 0, 0, 0);
            ab[mi] = __builtin_amdgcn_mfma_f32_16x16x32_bf16(av[mi], wb[ks], ab[mi], 0, 0, 0);
        }
    }
#pragma unroll
    for (int mi = 0; mi < 4; mi++) {
#pragma unroll
        for (int rr = 0; rr < 4; rr++) {
            int row = mi * 16 + lk * 4 + rr;
            int swz = (row & 7) << 4;
            *(short*)((char*)ot + row * 512 + ((col * 2) ^ swz)) = bfb(aa[mi][rr] + b1v);
            *(short*)((char*)ot + row * 512 + 256 + ((col * 2) ^ swz)) = bfb(ab[mi][rr]);
        }
    }
    __syncthreads();
    // coalesced LDS -> global copy (unswizzle)
#pragma unroll
    for (int it = 0; it < 4; it++) {
        int idx = it * 8192 + t * 16;
        int row = idx >> 9, off = idx & 511;
        int node = n0 + row;
        if (node < N_NODES) {
            int base = off & 256, lo = off & 255;
            int4v v = *(const int4v*)((char*)ot + row * 512 + base + (lo ^ ((row & 7) << 4)));
            *(int4v*)((char*)xab + (size_t)node * 512 + off) = v;
        }
    }
}

// ---------------------------------------------------------------- BN-fused A/B (layers 1,2):
// x = gamma*(y-mu)*rstd+beta (BN from raw stats), write x f32 + xb bf16,
// then A/B GEMM as k_ab.
__launch_bounds__(512, 2)
__global__ void k_abF(const float* __restrict__ y,
                      const float* __restrict__ stats,
                      const float* __restrict__ gamma, const float* __restrict__ beta,
                      const short* __restrict__ w1T, const float* __restrict__ b1,
                      float* __restrict__ x, __hip_bfloat16* __restrict__ xb,
                      short* __restrict__ xab) {
    __shared__ short xt[64 * 64];     // 8KB
    __shared__ short ot[64 * 256];    // 32KB
    const int t = threadIdx.x;
    const int wid = t >> 6, lane = t & 63, lrow = lane & 15, lk = lane >> 4;
    const int col = wid * 16 + lrow;
    const int n0 = blockIdx.x * 64;

    short8 wa[2], wb[2];
#pragma unroll
    for (int ks = 0; ks < 2; ks++) {
        wa[ks] = *(const short8*)((const char*)w1T + col * 256 + ks * 64 + lk * 16);
        wb[ks] = *(const short8*)((const char*)w1T + col * 256 + 128 + ks * 64 + lk * 16);
    }
    const float b1v = b1[col];

    {   // stage: read y, BN affine, write x + xb + LDS bf16
        int r = t >> 3, q = t & 7;
        int node = n0 + r;
        short8 s = {0, 0, 0, 0, 0, 0, 0, 0};
        if (node < N_NODES) {
            const float* yr = y + (size_t)node * DIM + q * 8;
            float4 f0 = *(const float4*)yr;
            float4 f1 = *(const float4*)(yr + 4);
            float v[8] = {f0.x, f0.y, f0.z, f0.w, f1.x, f1.y, f1.z, f1.w};
            float o[8];
#pragma unroll
            for (int i = 0; i < 8; i++) {
                int d = q * 8 + i;
                float mu = stats[d] * (1.f / N_NODES);
                float var = stats[64 + d] * (1.f / N_NODES) - mu * mu;
                float rstd = rsqrtf(var + BN_EPS);
                float a = gamma[d] * rstd;
                float b = beta[d] - mu * a;
                o[i] = a * v[i] + b;
                s[i] = bfb(o[i]);
            }
            float4 g0 = {o[0], o[1], o[2], o[3]};
            float4 g1 = {o[4], o[5], o[6], o[7]};
            *(float4*)(x + (size_t)node * DIM + q * 8) = g0;
            *(float4*)(x + (size_t)node * DIM + q * 8 + 4) = g1;
            *(short8*)((char*)xb + ((size_t)node * DIM + q * 8) * 2) = s;
        }
        *(int4v*)((char*)xt + r * 128 + ((q * 16) ^ ((r & 7) << 4))) = __builtin_bit_cast(int4v, s);
    }
    __syncthreads();

    f32x4 aa[4], ab[4];
#pragma unroll
    for (int mi = 0; mi < 4; mi++) { aa[mi] = (f32x4){0.f,0.f,0.f,0.f}; ab[mi] = (f32x4){0.f,0.f,0.f,0.f}; }
#pragma unroll
    for (int ks = 0; ks < 2; ks++) {
        int kb = ks * 64 + lk * 16;
        short8 av[4];
#pragma unroll
        for (int mi = 0; mi < 4; mi++) {
            int row = mi * 16 + lrow;
            av[mi] = *(const short8*)((const char*)xt + row * 128 + (kb ^ ((row & 7) << 4)));
        }
#pragma unroll
        for (int mi = 0; mi < 4; mi++) {
            aa[mi] = __builtin_amdgcn_mfma_f32_16x16x32_bf16(av[mi], wa[ks], aa[mi], 0, 0, 0);
            ab[mi] = __builtin_amdgcn_mfma_f32_16x16x32_bf16(av[mi], wb[ks], ab[mi], 0, 0, 0);
        }
    }
#pragma unroll
    for (int mi = 0; mi < 4; mi++) {
#pragma unroll
        for (int rr = 0; rr < 4; rr++) {
            int row = mi * 16 + lk * 4 + rr;
            int swz = (row & 7) << 4;
            *(short*)((char*)ot + row * 512 + ((col * 2) ^ swz)) = bfb(aa[mi][rr] + b1v);
            *(short*)((char*)ot + row * 512 + 256 + ((col * 2) ^ swz)) = bfb(ab[mi][rr]);
        }
    }
    __syncthreads();
#pragma unroll
    for (int it = 0; it < 4; it++) {
        int idx = it * 8192 + t * 16;
        int row = idx >> 9, off = idx & 511;
        int node = n0 + row;
        if (node < N_NODES) {
            int base = off & 256, lo = off & 255;
            int4v v = *(const int4v*)((char*)ot + row * 512 + base + (lo ^ ((row & 7) << 4)));
            *(int4v*)((char*)xab + (size_t)node * 512 + off) = v;
        }
    }
}

// ---------------------------------------------------------------- edge MLP (dst-sorted, A/B precomputed)
// 2 barriers/tile; next-tile gathers prefetched under the segment reduce.
__launch_bounds__(512, 6)
__global__ void k_edge(const short* __restrict__ xab,
                       const int4v* __restrict__ sedge,
                       const float* __restrict__ wl, const float* __restrict__ b2,
                       const short* __restrict__ w2T,
                       float* __restrict__ aggr) {
    __shared__ short ht[64 * 128];     // 16KB bf16 h-tile, rowbytes 256
    __shared__ float mt[64 * 128];     // 32KB f32 m-tile, rowbytes 512
    __shared__ int   dst_s[64];
    __shared__ int   seg_start[65];
    __shared__ int   seg_dst[64];
    __shared__ int   nseg_s;

    const int t = threadIdx.x;
    const int wid = t >> 6, lane = t & 63;
    const int lrow = lane & 15, lk = lane >> 4;
    const int r = t >> 3, q = t & 7;          // staging: 8 threads per edge row
    const int col = wid * 16 + lrow;          // GEMM output column

    short8 w2f[4];
#pragma unroll
    for (int ks = 0; ks < 4; ks++)
        w2f[ks] = *(const short8*)((const char*)w2T + col * 256 + ks * 64 + lk * 16);
    const float b2v = b2[col];
    float wlv[16];
#pragma unroll
    for (int i = 0; i < 16; i++) wlv[i] = wl[q * 16 + i];

    const int NT = N_EDGES / 64;              // 12500
    const int tile0 = (int)(((long)blockIdx.x * NT) / 1000);
    const int tile1 = (int)(((long)(blockIdx.x + 1) * NT) / 1000);

    // ---- prefetch state (tile t+1 loads issued under tile t's reduce)
    int4v ei;
    short8 ra0, ra1, rb0, rb1;
    {
        int e = tile0 * 64 + r;
        ei = sedge[e];
        const char* pa = (const char*)xab + (size_t)ei[1] * 512 + q * 32;
        const char* pb = (const char*)xab + (size_t)ei[0] * 512 + 256 + q * 32;
        ra0 = *(const short8*)pa;  ra1 = *(const short8*)(pa + 16);
        rb0 = *(const short8*)pb;  rb1 = *(const short8*)(pb + 16);
    }

    for (int tile = tile0; tile < tile1; ++tile) {
        // ---- stage h tile from prefetched regs: h = sp(A[dst]+B[src]+attr*wl)
        // safe pre-barrier: reduce(t-1) reads mt/seg_* only, never ht/dst_s
        {
            float at = __builtin_bit_cast(float, ei[2]);
            if (q == 0) dst_s[r] = ei[1];
            short8 h0, h1;
#pragma unroll
            for (int i = 0; i < 8; i++) {
                h0[i] = bfb(sp_(b2f(ra0[i]) + b2f(rb0[i]) + at * wlv[i]));
                h1[i] = bfb(sp_(b2f(ra1[i]) + b2f(rb1[i]) + at * wlv[8 + i]));
            }
            int swz = (r & 7) << 4;
            *(short8*)((char*)ht + r * 256 + ((q * 32) ^ swz)) = h0;
            *(short8*)((char*)ht + r * 256 + (((q * 32) + 16) ^ swz)) = h1;
        }
        __syncthreads();                       // A: ht + dst_s ready (and all waves
                                               //    done with previous reduce)

        // ---- segment list (wave 0)
        if (wid == 0) {
            int d = dst_s[lane];
            int prev = (lane == 0) ? -1 : dst_s[lane - 1];
            bool start = (d != prev);
            unsigned long long mask = __ballot(start);
            int sidx = __popcll(mask & ((1ull << lane) - 1));
            if (start) { seg_start[sidx] = lane; seg_dst[sidx] = d; }
            if (lane == 63) {
                int ns = __popcll(mask);
                nseg_s = ns;
                seg_start[ns] = 64;
            }
        }

        // ---- GEMM2: [64x128] @ [128x128], wave owns 16 cols
        f32x4 acc2[4];
#pragma unroll
        for (int mi = 0; mi < 4; mi++) acc2[mi] = (f32x4){0.f, 0.f, 0.f, 0.f};
#pragma unroll
        for (int ks = 0; ks < 4; ks++) {
            int kb = ks * 64 + lk * 16;
            short8 av[4];
#pragma unroll
            for (int mi = 0; mi < 4; mi++) {
                int row = mi * 16 + lrow;
                av[mi] = *(const short8*)((const char*)ht + row * 256 + (kb ^ ((row & 7) << 4)));
            }
#pragma unroll
            for (int mi = 0; mi < 4; mi++)
                acc2[mi] = __builtin_amdgcn_mfma_f32_16x16x32_bf16(av[mi], w2f[ks], acc2[mi], 0, 0, 0);
        }
        // epilogue: softplus(+b2) -> f32 m-tile
#pragma unroll
        for (int mi = 0; mi < 4; mi++) {
#pragma unroll
            for (int rr = 0; rr < 4; rr++) {
                int row = mi * 16 + lk * 4 + rr;
                *(float*)((char*)mt + row * 512 + ((col * 4) ^ ((row & 7) << 4))) = sp_(acc2[mi][rr] + b2v);
            }
        }
        __syncthreads();                       // C: m-tile + seg list visible

        // ---- prefetch next tile's gathers (latency hides under reduce)
        if (tile + 1 < tile1) {
            int e = (tile + 1) * 64 + r;
            ei = sedge[e];
            const char* pa = (const char*)xab + (size_t)ei[1] * 512 + q * 32;
            const char* pb = (const char*)xab + (size_t)ei[0] * 512 + 256 + q * 32;
            ra0 = *(const short8*)pa;  ra1 = *(const short8*)(pa + 16);
            rb0 = *(const short8*)pb;  rb1 = *(const short8*)(pb + 16);
        }

        // ---- per-segment reduce + one atomicAdd per (segment, col)
        {
            int nseg = nseg_s;
            int rcol = t & 127, h = t >> 7;    // 4 thread-groups over segments
            for (int s = h; s < nseg; s += 4) {
                int r0 = seg_start[s], r1 = seg_start[s + 1];
                float sum = 0.f;
                for (int rr = r0; rr < r1; rr++)
                    sum += *(const float*)((const char*)mt + rr * 512 + ((rcol * 4) ^ ((rr & 7) << 4)));
                atomicAdd(&aggr[(size_t)seg_dst[s] * HID + rcol], sum);
            }
        }
        // no barrier: next staging writes only ht/dst_s (not read by reduce);
        // barrier A fences seg_*/mt reuse collectively.
    }
}

// ---------------------------------------------------------------- node MLP + BN partial stats
__launch_bounds__(256, 3)
__global__ void k_node(const __hip_bfloat16* __restrict__ xb,
                       const float* __restrict__ xf,
                       const float* __restrict__ aggr,
                       const short* __restrict__ w1T, const float* __restrict__ b1,
                       const short* __restrict__ w2T, const float* __restrict__ b2,
                       float* __restrict__ y, float* __restrict__ stats) {
    __shared__ short at[64 * 192];    // 24KB rowbytes 384
    __shared__ short ht[64 * 128];    // 16KB

    const int t = threadIdx.x;
    const int wid = t >> 6, lane = t & 63, lrow = lane & 15, lk = lane >> 4;
    const int n0 = blockIdx.x * 64;

    const int nc0 = wid * 32;
    short8 w1f[6][2];
    float b1v[2];
#pragma unroll
    for (int ni = 0; ni < 2; ni++) {
        int col = nc0 + ni * 16 + lrow;
#pragma unroll
        for (int ks = 0; ks < 6; ks++) {
            int kb = ks * 64 + lk * 16;
            w1f[ks][ni] = *(const short8*)((const char*)w1T + col * 384 + kb);
        }
        b1v[ni] = b1[col];
    }
    const int nc2 = wid * 16;
    const int col2 = nc2 + lrow;
    short8 w2f[4];
#pragma unroll
    for (int ks = 0; ks < 4; ks++)
        w2f[ks] = *(const short8*)((const char*)w2T + col2 * 256 + ks * 64 + lk * 16);
    const float b2v = b2[col2];

    if (t < 64) {
        int node = n0 + t;
        if (node < N_NODES) {
            const __hip_bfloat16* xr = xb + (size_t)node * DIM;
#pragma unroll
            for (int i = 0; i < 8; i++) {
                int4v v = *(const int4v*)(xr + i * 8);
                *(int4v*)((char*)at + t * 384 + ((i * 16) ^ ((t & 7) << 4))) = v;
            }
        } else {
            int4v z = {0, 0, 0, 0};
#pragma unroll
            for (int i = 0; i < 8; i++)
                *(int4v*)((char*)at + t * 384 + ((i * 16) ^ ((t & 7) << 4))) = z;
        }
    }
    {
        int r = t >> 2, q = t & 3;
        int node = n0 + r;
#pragma unroll
        for (int i = 0; i < 4; i++) {
            short8 s = {0, 0, 0, 0, 0, 0, 0, 0};
            if (node < N_NODES) {
                const float* ar = aggr + (size_t)node * HID + q * 32 + i * 8;
                float4 f0 = *(const float4*)ar;
                float4 f1 = *(const float4*)(ar + 4);
                s = (short8){bfb(f0.x), bfb(f0.y), bfb(f0.z), bfb(f0.w),
                             bfb(f1.x), bfb(f1.y), bfb(f1.z), bfb(f1.w)};
            }
            int cb = 128 + q * 64 + i * 16;
            *(short8*)((char*)at + r * 384 + (cb ^ ((r & 7) << 4))) = s;
        }
    }
    __syncthreads();

    f32x4 acc[4][2];
#pragma unroll
    for (int mi = 0; mi < 4; mi++)
#pragma unroll
        for (int ni = 0; ni < 2; ni++) acc[mi][ni] = (f32x4){0.f, 0.f, 0.f, 0.f};
#pragma unroll
    for (int ks = 0; ks < 6; ks++) {
        int kb = ks * 64 + lk * 16;
        short8 av[4];
#pragma unroll
        for (int mi = 0; mi < 4; mi++) {
            int row = mi * 16 + lrow;
            av[mi] = *(const short8*)((const char*)at + row * 384 + (kb ^ ((row & 7) << 4)));
        }
#pragma unroll
        for (int mi = 0; mi < 4; mi++)
#pragma unroll
            for (int ni = 0; ni < 2; ni++)
                acc[mi][ni] = __builtin_amdgcn_mfma_f32_16x16x32_bf16(av[mi], w1f[ks][ni], acc[mi][ni], 0, 0, 0);
    }
#pragma unroll
    for (int mi = 0; mi < 4; mi++) {
#pragma unroll
        for (int ni = 0; ni < 2; ni++) {
            int col = nc0 + ni * 16 + lrow;
#pragma unroll
            for (int rr = 0; rr < 4; rr++) {
                int row = mi * 16 + lk * 4 + rr;
                float val = sp_(acc[mi][ni][rr] + b1v[ni]);
                *(short*)((char*)ht + row * 256 + ((col * 2) ^ ((row & 7) << 4))) = bfb(val);
            }
        }
    }
    __syncthreads();

    f32x4 acc2[4];
#pragma unroll
    for (int mi = 0; mi < 4; mi++) acc2[mi] = (f32x4){0.f, 0.f, 0.f, 0.f};
#pragma unroll
    for (int ks = 0; ks < 4; ks++) {
        int kb = ks * 64 + lk * 16;
        short8 av[4];
#pragma unroll
        for (int mi = 0; mi < 4; mi++) {
            int row = mi * 16 + lrow;
            av[mi] = *(const short8*)((const char*)ht + row * 256 + (kb ^ ((row & 7) << 4)));
        }
#pragma unroll
        for (int mi = 0; mi < 4; mi++)
            acc2[mi] = __builtin_amdgcn_mfma_f32_16x16x32_bf16(av[mi], w2f[ks], acc2[mi], 0, 0, 0);
    }
    float s1 = 0.f, s2 = 0.f;
#pragma unroll
    for (int mi = 0; mi < 4; mi++) {
#pragma unroll
        for (int rr = 0; rr < 4; rr++) {
            int row = mi * 16 + lk * 4 + rr;
            int node = n0 + row;
            if (node < N_NODES) {
                float v = acc2[mi][rr] + b2v + xf[(size_t)node * DIM + col2];
                y[(size_t)node * DIM + col2] = v;
                s1 += v;
                s2 += v * v;
            }
        }
    }
    s1 += __shfl_xor(s1, 16); s1 += __shfl_xor(s1, 32);
    s2 += __shfl_xor(s2, 16); s2 += __shfl_xor(s2, 32);
    if (lane < 16) {
        atomicAdd(&stats[col2], s1);
        atomicAdd(&stats[64 + col2], s2);
    }
}

// ---------------------------------------------------------------- pool: per-graph mean + final BN (from raw stats)
__global__ void k_pool2(const int* __restrict__ gstart, const float* __restrict__ y,
                        const float* __restrict__ stats,
                        const float* __restrict__ gamma, const float* __restrict__ beta,
                        float* __restrict__ pooled) {
    __shared__ float red[256];
    const int g = blockIdx.x, t = threadIdx.x;
    const int d = t & 63, nl = t >> 6;
    const int s = gstart[g], e = gstart[g + 1];
    float sum = 0.f;
    for (int n = s + nl; n < e; n += 4)
        sum += y[(size_t)n * DIM + d];
    red[t] = sum;
    __syncthreads();
    if (t < 64) {
        float tot = red[t] + red[t + 64] + red[t + 128] + red[t + 192];
        int c = e - s;
        float mean = tot / fmaxf((float)c, 1.f);
        float mu = stats[t] * (1.f / N_NODES);
        float var = stats[64 + t] * (1.f / N_NODES) - mu * mu;
        float rstd = rsqrtf(var + BN_EPS);
        float a = gamma[t] * rstd;
        float b = beta[t] - mu * a;
        pooled[g * DIM + t] = a * mean + b;   // == mean(a*y+b)
    }
}

// ---------------------------------------------------------------- output MLP (f32)
__global__ void k_out(const float* __restrict__ pooled,
                      const float* __restrict__ W1, const float* __restrict__ b1,
                      const float* __restrict__ W2, const float* __restrict__ b2,
                      float* __restrict__ out) {
    __shared__ float pl[64];
    __shared__ float wsum[2];
    int g = blockIdx.x, t = threadIdx.x;
    if (t < 64) pl[t] = pooled[g * 64 + t];
    __syncthreads();
    float a = b1[t];
#pragma unroll
    for (int d = 0; d < 64; d++) a += pl[d] * W1[d * 128 + t];
    float c = sp_(a) * W2[t];
#pragma unroll
    for (int off = 32; off >= 1; off >>= 1) c += __shfl_down(c, off);
    int lane = t & 63, wid = t >> 6;
    if (lane == 0) wsum[wid] = c;
    __syncthreads();
    if (t == 0) out[g] = wsum[0] + wsum[1] + b2[0];
}

// ---------------------------------------------------------------- launch
extern "C" void kernel_launch(void* const* d_in, const int* in_sizes, int n_in,
                              void* d_out, int out_size, void* d_ws, size_t ws_size,
                              hipStream_t stream) {
    const int*   az    = (const int*)d_in[0];
    const int*   ei    = (const int*)d_in[1];
    const float* eattr = (const float*)d_in[2];
    const int*   batch = (const int*)d_in[3];
    const float* emb   = (const float*)d_in[4];
    const float* eW1   = (const float*)d_in[5];
    const float* eb1   = (const float*)d_in[6];
    const float* eW2   = (const float*)d_in[7];
    const float* eb2   = (const float*)d_in[8];
    const float* nW1   = (const float*)d_in[9];
    const float* nb1   = (const float*)d_in[10];
    const float* nW2   = (const float*)d_in[11];
    const float* nb2   = (const float*)d_in[12];
    const float* gam   = (const float*)d_in[13];
    const float* bet   = (const float*)d_in[14];
    const float* oW1   = (const float*)d_in[15];
    const float* ob1   = (const float*)d_in[16];
    const float* oW2   = (const float*)d_in[17];
    const float* ob2   = (const float*)d_in[18];
    const int* esrc = ei;
    const int* edst = ei + N_EDGES;

    float* x     = (float*)d_ws;
    float* y     = x + (size_t)N_NODES * DIM;
    float* aggr  = y + (size_t)N_NODES * DIM;
    float* stats = aggr + (size_t)N_NODES * HID;     // 256 floats (adjacent: joint memset)
    float* pooled = stats + 256;                     // [128][64]
    __hip_bfloat16* xb = (__hip_bfloat16*)(pooled + NGRAPH * DIM);
    short* ew1T = (short*)(xb + (size_t)N_NODES * DIM);   // [3][128][128]
    short* ew2T = ew1T + 3 * 128 * 128;                   // [3][128][128]
    short* nw1T = ew2T + 3 * 128 * 128;                   // [3][128][192]
    short* nw2T = nw1T + 3 * 128 * 192;                   // [3][64][128]
    int*   cursor = (int*)(nw2T + 3 * 64 * 128);          // [50000]
    int4v* sedge  = (int4v*)(cursor + N_NODES + 48);      // [800000] 16B recs (align)
    int*   gstart = (int*)(sedge + N_EDGES);              // [129]
    short* xab    = (short*)(gstart + 256);               // [50000][256] bf16

    k_embed<<<(N_NODES * DIM + 255) / 256, 256, 0, stream>>>(az, emb, x, xb);

    // pre-transpose all layer weights to bf16 [n][k]
    k_wprep<<<dim3(64, 3), 256, 0, stream>>>(eW1, ew1T, 128 * 128, 7, 129 * 128);
    k_wprep<<<dim3(64, 3), 256, 0, stream>>>(eW2, ew2T, 128 * 128, 7, 128 * 128);
    k_wprep<<<dim3(96, 3), 256, 0, stream>>>(nW1, nw1T, 192 * 128, 7, 192 * 128);
    k_wprep<<<dim3(32, 3), 256, 0, stream>>>(nW2, nw2T, 128 * 64, 6, 128 * 64);

    // counting sort of edges by dst (once per launch)
    hipMemsetAsync(cursor, 0, N_NODES * sizeof(int), stream);
    k_hist<<<(N_EDGES + 255) / 256, 256, 0, stream>>>(edst, cursor);
    k_scan<<<1, 1024, 0, stream>>>(cursor, cursor);   // in-place: per-thread own-index RMW
    k_scatter<<<(N_EDGES + 255) / 256, 256, 0, stream>>>(esrc, edst, eattr, cursor, sedge);
    k_gbounds<<<1, 256, 0, stream>>>(batch, gstart);

    for (int l = 0; l < 3; l++) {
        // A/B precompute (BN of previous layer fused in for l>=1).
        // NOTE: must run BEFORE the memset below (k_abF reads prev stats).
        if (l == 0)
            k_ab<<<(N_NODES + 63) / 64, 512, 0, stream>>>(xb, ew1T, eb1, xab);
        else
            k_abF<<<(N_NODES + 63) / 64, 512, 0, stream>>>(y, stats,
                                                           gam + (l - 1) * 64, bet + (l - 1) * 64,
                                                           ew1T + (size_t)l * 128 * 128, eb1 + l * 128,
                                                           x, xb, xab);
        hipMemsetAsync(aggr, 0, ((size_t)N_NODES * HID + 256) * sizeof(float), stream);
        k_edge<<<1000, 512, 0, stream>>>(xab, sedge,
                                         eW1 + (size_t)l * 129 * 128 + 128 * 128,
                                         eb2 + l * 128,
                                         ew2T + (size_t)l * 128 * 128,
                                         aggr);
        k_node<<<(N_NODES + 63) / 64, 256, 0, stream>>>(xb, x, aggr,
                                                        nw1T + (size_t)l * 128 * 192, nb1 + l * 128,
                                                        nw2T + (size_t)l * 64 * 128, nb2 + l * 64,
                                                        y, stats);
    }

    k_pool2<<<NGRAPH, 256, 0, stream>>>(gstart, y, stats, gam + 2 * 64, bet + 2 * 64, pooled);
    k_out<<<NGRAPH, 128, 0, stream>>>(pooled, oW1, ob1, oW2, ob2, (float*)d_out);
}

// Round 13
// 937.276 us; speedup vs baseline: 1.4656x; 1.4656x over previous
//
#include <hip/hip_runtime.h>
#include <hip/hip_bf16.h>

#define N_NODES 50000
#define N_EDGES 800000
#define DIM 64
#define HID 128
#define NGRAPH 128
#define BN_EPS 1e-5f

typedef __attribute__((ext_vector_type(8))) short short8;
typedef __attribute__((ext_vector_type(4))) short short4v;
typedef __attribute__((ext_vector_type(4))) float f32x4;
typedef __attribute__((ext_vector_type(4))) int int4v;

__device__ __forceinline__ float sp_(float v) {
    // softplus via hardware v_exp_f32 / v_log_f32 (~1e-6 abs err, fine at bf16)
    return fmaxf(v, 0.f) + __logf(1.f + __expf(-fabsf(v)));
}
__device__ __forceinline__ short bfb(float f) {
    __hip_bfloat16 h = __float2bfloat16(f);
    return __builtin_bit_cast(short, h);
}
__device__ __forceinline__ float b2f(short s) {
    unsigned u = ((unsigned)(unsigned short)s) << 16;
    return __builtin_bit_cast(float, u);
}

// ---------------------------------------------------------------- embed
__global__ void k_embed(const int* __restrict__ az, const float* __restrict__ emb,
                        float* __restrict__ x, __hip_bfloat16* __restrict__ xb) {
    int idx = blockIdx.x * 256 + threadIdx.x;
    if (idx >= N_NODES * DIM) return;
    int n = idx >> 6;
    int d = idx & 63;
    float v = emb[az[n] * DIM + d];
    x[idx] = v;
    xb[idx] = __float2bfloat16(v);
}

// ---------------------------------------------------------------- weight prep:
// transpose f32 [K][N] (row-major) -> bf16 [N][K]; blockIdx.y = layer
__global__ void k_wprep(const float* __restrict__ src, short* __restrict__ dst,
                        int total, int nshift, int srcStride) {
    int l = blockIdx.y;
    int idx = blockIdx.x * 256 + threadIdx.x;
    if (idx >= total) return;
    int K = total >> nshift;
    int k = idx >> nshift;
    int n = idx & ((1 << nshift) - 1);
    dst[(size_t)l * total + n * K + k] = bfb(src[(size_t)l * srcStride + idx]);
}

// ---------------------------------------------------------------- counting sort by dst
__global__ void k_hist(const int* __restrict__ edst, int* __restrict__ deg) {
    int e = blockIdx.x * 256 + threadIdx.x;
    if (e < N_EDGES) atomicAdd(&deg[edst[e]], 1);
}

// single block, 1024 threads: exclusive prefix sum deg -> cursor
__global__ void k_scan(const int* __restrict__ deg, int* __restrict__ cursor) {
    __shared__ int wsum[16];
    __shared__ int carry;
    const int t = threadIdx.x, lane = t & 63, w = t >> 6;
    if (t == 0) carry = 0;
    __syncthreads();
    for (int base = 0; base < N_NODES; base += 1024) {
        int i = base + t;
        int v = (i < N_NODES) ? deg[i] : 0;
        int s = v;
#pragma unroll
        for (int off = 1; off < 64; off <<= 1) {
            int u = __shfl_up(s, off);
            if (lane >= off) s += u;
        }
        if (lane == 63) wsum[w] = s;
        __syncthreads();
        if (w == 0) {
            int ws = (lane < 16) ? wsum[lane] : 0;
#pragma unroll
            for (int off = 1; off < 16; off <<= 1) {
                int u = __shfl_up(ws, off);
                if (lane >= off) ws += u;
            }
            if (lane < 16) wsum[lane] = ws;
        }
        __syncthreads();
        int woff = (w == 0) ? 0 : wsum[w - 1];
        int excl = carry + woff + s - v;
        if (i < N_NODES) cursor[i] = excl;
        __syncthreads();
        if (t == 1023) carry += wsum[15];
        __syncthreads();
    }
}

// scatter into interleaved edge records {src, dst, attr_bits, 0}
__global__ void k_scatter(const int* __restrict__ esrc, const int* __restrict__ edst,
                          const float* __restrict__ eattr, int* __restrict__ cursor,
                          int4v* __restrict__ sedge) {
    int e = blockIdx.x * 256 + threadIdx.x;
    if (e >= N_EDGES) return;
    int d = edst[e];
    int pos = atomicAdd(&cursor[d], 1);
    int4v rec = {esrc[e], d, __builtin_bit_cast(int, eattr[e]), 0};
    sedge[pos] = rec;
}

// ---------------------------------------------------------------- graph bounds
__global__ void k_gbounds(const int* __restrict__ batch, int* __restrict__ gstart) {
    int g = threadIdx.x;
    if (g > NGRAPH) return;
    int lo = 0, hi = N_NODES;
    while (lo < hi) {
        int mid = (lo + hi) >> 1;
        if (batch[mid] < g) lo = mid + 1; else hi = mid;
    }
    gstart[g] = lo;
}

// ---------------------------------------------------------------- per-node A/B (layer 0):
// A[n] = x[n]@W1[0:64] + b1, B[n] = x[n]@W1[64:128]
// output xab[n][0:128]=A bf16, [128:256]=B bf16
__launch_bounds__(512, 2)
__global__ void k_ab(const __hip_bfloat16* __restrict__ xb,
                     const short* __restrict__ w1T, const float* __restrict__ b1,
                     short* __restrict__ xab) {
    __shared__ short xt[64 * 64];     // 8KB, rowbytes 128
    __shared__ short ot[64 * 256];    // 32KB, rowbytes 512
    const int t = threadIdx.x;
    const int wid = t >> 6, lane = t & 63, lrow = lane & 15, lk = lane >> 4;
    const int col = wid * 16 + lrow;
    const int n0 = blockIdx.x * 64;

    short8 wa[2], wb[2];
#pragma unroll
    for (int ks = 0; ks < 2; ks++) {
        wa[ks] = *(const short8*)((const char*)w1T + col * 256 + ks * 64 + lk * 16);
        wb[ks] = *(const short8*)((const char*)w1T + col * 256 + 128 + ks * 64 + lk * 16);
    }
    const float b1v = b1[col];

    {   // stage x tile
        int r = t >> 3, q = t & 7;
        int node = n0 + r;
        int4v v = {0, 0, 0, 0};
        if (node < N_NODES) v = *(const int4v*)(xb + (size_t)node * DIM + q * 8);
        *(int4v*)((char*)xt + r * 128 + ((q * 16) ^ ((r & 7) << 4))) = v;
    }
    __syncthreads();

    f32x4 aa[4], ab[4];
#pragma unroll
    for (int mi = 0; mi < 4; mi++) { aa[mi] = (f32x4){0.f,0.f,0.f,0.f}; ab[mi] = (f32x4){0.f,0.f,0.f,0.f}; }
#pragma unroll
    for (int ks = 0; ks < 2; ks++) {
        int kb = ks * 64 + lk * 16;
        short8 av[4];
#pragma unroll
        for (int mi = 0; mi < 4; mi++) {
            int row = mi * 16 + lrow;
            av[mi] = *(const short8*)((const char*)xt + row * 128 + (kb ^ ((row & 7) << 4)));
        }
#pragma unroll
        for (int mi = 0; mi < 4; mi++) {
            aa[mi] = __builtin_amdgcn_mfma_f32_16x16x32_bf16(av[mi], wa[ks], aa[mi], 0, 0, 0);
            ab[mi] = __builtin_amdgcn_mfma_f32_16x16x32_bf16(av[mi], wb[ks], ab[mi], 0, 0, 0);
        }
    }
#pragma unroll
    for (int mi = 0; mi < 4; mi++) {
#pragma unroll
        for (int rr = 0; rr < 4; rr++) {
            int row = mi * 16 + lk * 4 + rr;
            int swz = (row & 7) << 4;
            *(short*)((char*)ot + row * 512 + ((col * 2) ^ swz)) = bfb(aa[mi][rr] + b1v);
            *(short*)((char*)ot + row * 512 + 256 + ((col * 2) ^ swz)) = bfb(ab[mi][rr]);
        }
    }
    __syncthreads();
    // coalesced LDS -> global copy (unswizzle)
#pragma unroll
    for (int it = 0; it < 4; it++) {
        int idx = it * 8192 + t * 16;
        int row = idx >> 9, off = idx & 511;
        int node = n0 + row;
        if (node < N_NODES) {
            int base = off & 256, lo = off & 255;
            int4v v = *(const int4v*)((char*)ot + row * 512 + base + (lo ^ ((row & 7) << 4)));
            *(int4v*)((char*)xab + (size_t)node * 512 + off) = v;
        }
    }
}

// ---------------------------------------------------------------- BN-fused A/B (layers 1,2):
// x = gamma*(y-mu)*rstd+beta (BN from raw stats), write x f32 + xb bf16,
// then A/B GEMM as k_ab.
__launch_bounds__(512, 2)
__global__ void k_abF(const float* __restrict__ y,
                      const float* __restrict__ stats,
                      const float* __restrict__ gamma, const float* __restrict__ beta,
                      const short* __restrict__ w1T, const float* __restrict__ b1,
                      float* __restrict__ x, __hip_bfloat16* __restrict__ xb,
                      short* __restrict__ xab) {
    __shared__ short xt[64 * 64];     // 8KB
    __shared__ short ot[64 * 256];    // 32KB
    const int t = threadIdx.x;
    const int wid = t >> 6, lane = t & 63, lrow = lane & 15, lk = lane >> 4;
    const int col = wid * 16 + lrow;
    const int n0 = blockIdx.x * 64;

    short8 wa[2], wb[2];
#pragma unroll
    for (int ks = 0; ks < 2; ks++) {
        wa[ks] = *(const short8*)((const char*)w1T + col * 256 + ks * 64 + lk * 16);
        wb[ks] = *(const short8*)((const char*)w1T + col * 256 + 128 + ks * 64 + lk * 16);
    }
    const float b1v = b1[col];

    {   // stage: read y, BN affine, write x + xb + LDS bf16
        int r = t >> 3, q = t & 7;
        int node = n0 + r;
        short8 s = {0, 0, 0, 0, 0, 0, 0, 0};
        if (node < N_NODES) {
            const float* yr = y + (size_t)node * DIM + q * 8;
            float4 f0 = *(const float4*)yr;
            float4 f1 = *(const float4*)(yr + 4);
            float v[8] = {f0.x, f0.y, f0.z, f0.w, f1.x, f1.y, f1.z, f1.w};
            float o[8];
#pragma unroll
            for (int i = 0; i < 8; i++) {
                int d = q * 8 + i;
                float mu = stats[d] * (1.f / N_NODES);
                float var = stats[64 + d] * (1.f / N_NODES) - mu * mu;
                float rstd = rsqrtf(var + BN_EPS);
                float a = gamma[d] * rstd;
                float b = beta[d] - mu * a;
                o[i] = a * v[i] + b;
                s[i] = bfb(o[i]);
            }
            float4 g0 = {o[0], o[1], o[2], o[3]};
            float4 g1 = {o[4], o[5], o[6], o[7]};
            *(float4*)(x + (size_t)node * DIM + q * 8) = g0;
            *(float4*)(x + (size_t)node * DIM + q * 8 + 4) = g1;
            *(short8*)((char*)xb + ((size_t)node * DIM + q * 8) * 2) = s;
        }
        *(int4v*)((char*)xt + r * 128 + ((q * 16) ^ ((r & 7) << 4))) = __builtin_bit_cast(int4v, s);
    }
    __syncthreads();

    f32x4 aa[4], ab[4];
#pragma unroll
    for (int mi = 0; mi < 4; mi++) { aa[mi] = (f32x4){0.f,0.f,0.f,0.f}; ab[mi] = (f32x4){0.f,0.f,0.f,0.f}; }
#pragma unroll
    for (int ks = 0; ks < 2; ks++) {
        int kb = ks * 64 + lk * 16;
        short8 av[4];
#pragma unroll
        for (int mi = 0; mi < 4; mi++) {
            int row = mi * 16 + lrow;
            av[mi] = *(const short8*)((const char*)xt + row * 128 + (kb ^ ((row & 7) << 4)));
        }
#pragma unroll
        for (int mi = 0; mi < 4; mi++) {
            aa[mi] = __builtin_amdgcn_mfma_f32_16x16x32_bf16(av[mi], wa[ks], aa[mi], 0, 0, 0);
            ab[mi] = __builtin_amdgcn_mfma_f32_16x16x32_bf16(av[mi], wb[ks], ab[mi], 0, 0, 0);
        }
    }
#pragma unroll
    for (int mi = 0; mi < 4; mi++) {
#pragma unroll
        for (int rr = 0; rr < 4; rr++) {
            int row = mi * 16 + lk * 4 + rr;
            int swz = (row & 7) << 4;
            *(short*)((char*)ot + row * 512 + ((col * 2) ^ swz)) = bfb(aa[mi][rr] + b1v);
            *(short*)((char*)ot + row * 512 + 256 + ((col * 2) ^ swz)) = bfb(ab[mi][rr]);
        }
    }
    __syncthreads();
#pragma unroll
    for (int it = 0; it < 4; it++) {
        int idx = it * 8192 + t * 16;
        int row = idx >> 9, off = idx & 511;
        int node = n0 + row;
        if (node < N_NODES) {
            int base = off & 256, lo = off & 255;
            int4v v = *(const int4v*)((char*)ot + row * 512 + base + (lo ^ ((row & 7) << 4)));
            *(int4v*)((char*)xab + (size_t)node * 512 + off) = v;
        }
    }
}

// ---------------------------------------------------------------- edge MLP (dst-sorted, A/B precomputed)
// 2 barriers/tile; next-tile gathers prefetched under the segment reduce.
// __launch_bounds__(512,4): VGPR cap 128. (512,6) caps at ~85 -> spills the
// prefetch+weight regs to scratch (round 12: FETCH 87->561MB, 1.8x slower).
__launch_bounds__(512, 4)
__global__ void k_edge(const short* __restrict__ xab,
                       const int4v* __restrict__ sedge,
                       const float* __restrict__ wl, const float* __restrict__ b2,
                       const short* __restrict__ w2T,
                       float* __restrict__ aggr) {
    __shared__ short ht[64 * 128];     // 16KB bf16 h-tile, rowbytes 256
    __shared__ float mt[64 * 128];     // 32KB f32 m-tile, rowbytes 512
    __shared__ int   dst_s[64];
    __shared__ int   seg_start[65];
    __shared__ int   seg_dst[64];
    __shared__ int   nseg_s;

    const int t = threadIdx.x;
    const int wid = t >> 6, lane = t & 63;
    const int lrow = lane & 15, lk = lane >> 4;
    const int r = t >> 3, q = t & 7;          // staging: 8 threads per edge row
    const int col = wid * 16 + lrow;          // GEMM output column

    short8 w2f[4];
#pragma unroll
    for (int ks = 0; ks < 4; ks++)
        w2f[ks] = *(const short8*)((const char*)w2T + col * 256 + ks * 64 + lk * 16);
    const float b2v = b2[col];
    float wlv[16];
#pragma unroll
    for (int i = 0; i < 16; i++) wlv[i] = wl[q * 16 + i];

    const int NT = N_EDGES / 64;              // 12500
    const int tile0 = (int)(((long)blockIdx.x * NT) / 1000);
    const int tile1 = (int)(((long)(blockIdx.x + 1) * NT) / 1000);

    // ---- prefetch state (tile t+1 loads issued under tile t's reduce)
    int4v ei;
    short8 ra0, ra1, rb0, rb1;
    {
        int e = tile0 * 64 + r;
        ei = sedge[e];
        const char* pa = (const char*)xab + (size_t)ei[1] * 512 + q * 32;
        const char* pb = (const char*)xab + (size_t)ei[0] * 512 + 256 + q * 32;
        ra0 = *(const short8*)pa;  ra1 = *(const short8*)(pa + 16);
        rb0 = *(const short8*)pb;  rb1 = *(const short8*)(pb + 16);
    }

    for (int tile = tile0; tile < tile1; ++tile) {
        // ---- stage h tile from prefetched regs: h = sp(A[dst]+B[src]+attr*wl)
        // safe pre-barrier: reduce(t-1) reads mt/seg_* only, never ht/dst_s
        {
            float at = __builtin_bit_cast(float, ei[2]);
            if (q == 0) dst_s[r] = ei[1];
            short8 h0, h1;
#pragma unroll
            for (int i = 0; i < 8; i++) {
                h0[i] = bfb(sp_(b2f(ra0[i]) + b2f(rb0[i]) + at * wlv[i]));
                h1[i] = bfb(sp_(b2f(ra1[i]) + b2f(rb1[i]) + at * wlv[8 + i]));
            }
            int swz = (r & 7) << 4;
            *(short8*)((char*)ht + r * 256 + ((q * 32) ^ swz)) = h0;
            *(short8*)((char*)ht + r * 256 + (((q * 32) + 16) ^ swz)) = h1;
        }
        __syncthreads();                       // A: ht + dst_s ready (and all waves
                                               //    done with previous reduce)

        // ---- segment list (wave 0)
        if (wid == 0) {
            int d = dst_s[lane];
            int prev = (lane == 0) ? -1 : dst_s[lane - 1];
            bool start = (d != prev);
            unsigned long long mask = __ballot(start);
            int sidx = __popcll(mask & ((1ull << lane) - 1));
            if (start) { seg_start[sidx] = lane; seg_dst[sidx] = d; }
            if (lane == 63) {
                int ns = __popcll(mask);
                nseg_s = ns;
                seg_start[ns] = 64;
            }
        }

        // ---- GEMM2: [64x128] @ [128x128], wave owns 16 cols
        f32x4 acc2[4];
#pragma unroll
        for (int mi = 0; mi < 4; mi++) acc2[mi] = (f32x4){0.f, 0.f, 0.f, 0.f};
#pragma unroll
        for (int ks = 0; ks < 4; ks++) {
            int kb = ks * 64 + lk * 16;
            short8 av[4];
#pragma unroll
            for (int mi = 0; mi < 4; mi++) {
                int row = mi * 16 + lrow;
                av[mi] = *(const short8*)((const char*)ht + row * 256 + (kb ^ ((row & 7) << 4)));
            }
#pragma unroll
            for (int mi = 0; mi < 4; mi++)
                acc2[mi] = __builtin_amdgcn_mfma_f32_16x16x32_bf16(av[mi], w2f[ks], acc2[mi], 0, 0, 0);
        }
        // epilogue: softplus(+b2) -> f32 m-tile
#pragma unroll
        for (int mi = 0; mi < 4; mi++) {
#pragma unroll
            for (int rr = 0; rr < 4; rr++) {
                int row = mi * 16 + lk * 4 + rr;
                *(float*)((char*)mt + row * 512 + ((col * 4) ^ ((row & 7) << 4))) = sp_(acc2[mi][rr] + b2v);
            }
        }
        __syncthreads();                       // C: m-tile + seg list visible

        // ---- prefetch next tile's gathers (latency hides under reduce)
        if (tile + 1 < tile1) {
            int e = (tile + 1) * 64 + r;
            ei = sedge[e];
            const char* pa = (const char*)xab + (size_t)ei[1] * 512 + q * 32;
            const char* pb = (const char*)xab + (size_t)ei[0] * 512 + 256 + q * 32;
            ra0 = *(const short8*)pa;  ra1 = *(const short8*)(pa + 16);
            rb0 = *(const short8*)pb;  rb1 = *(const short8*)(pb + 16);
        }

        // ---- per-segment reduce + one atomicAdd per (segment, col)
        {
            int nseg = nseg_s;
            int rcol = t & 127, h = t >> 7;    // 4 thread-groups over segments
            for (int s = h; s < nseg; s += 4) {
                int r0 = seg_start[s], r1 = seg_start[s + 1];
                float sum = 0.f;
                for (int rr = r0; rr < r1; rr++)
                    sum += *(const float*)((const char*)mt + rr * 512 + ((rcol * 4) ^ ((rr & 7) << 4)));
                atomicAdd(&aggr[(size_t)seg_dst[s] * HID + rcol], sum);
            }
        }
        // no barrier: next staging writes only ht/dst_s (not read by reduce);
        // barrier A fences seg_*/mt reuse collectively.
    }
}

// ---------------------------------------------------------------- node MLP + BN partial stats
__launch_bounds__(256, 3)
__global__ void k_node(const __hip_bfloat16* __restrict__ xb,
                       const float* __restrict__ xf,
                       const float* __restrict__ aggr,
                       const short* __restrict__ w1T, const float* __restrict__ b1,
                       const short* __restrict__ w2T, const float* __restrict__ b2,
                       float* __restrict__ y, float* __restrict__ stats) {
    __shared__ short at[64 * 192];    // 24KB rowbytes 384
    __shared__ short ht[64 * 128];    // 16KB

    const int t = threadIdx.x;
    const int wid = t >> 6, lane = t & 63, lrow = lane & 15, lk = lane >> 4;
    const int n0 = blockIdx.x * 64;

    const int nc0 = wid * 32;
    short8 w1f[6][2];
    float b1v[2];
#pragma unroll
    for (int ni = 0; ni < 2; ni++) {
        int col = nc0 + ni * 16 + lrow;
#pragma unroll
        for (int ks = 0; ks < 6; ks++) {
            int kb = ks * 64 + lk * 16;
            w1f[ks][ni] = *(const short8*)((const char*)w1T + col * 384 + kb);
        }
        b1v[ni] = b1[col];
    }
    const int nc2 = wid * 16;
    const int col2 = nc2 + lrow;
    short8 w2f[4];
#pragma unroll
    for (int ks = 0; ks < 4; ks++)
        w2f[ks] = *(const short8*)((const char*)w2T + col2 * 256 + ks * 64 + lk * 16);
    const float b2v = b2[col2];

    if (t < 64) {
        int node = n0 + t;
        if (node < N_NODES) {
            const __hip_bfloat16* xr = xb + (size_t)node * DIM;
#pragma unroll
            for (int i = 0; i < 8; i++) {
                int4v v = *(const int4v*)(xr + i * 8);
                *(int4v*)((char*)at + t * 384 + ((i * 16) ^ ((t & 7) << 4))) = v;
            }
        } else {
            int4v z = {0, 0, 0, 0};
#pragma unroll
            for (int i = 0; i < 8; i++)
                *(int4v*)((char*)at + t * 384 + ((i * 16) ^ ((t & 7) << 4))) = z;
        }
    }
    {
        int r = t >> 2, q = t & 3;
        int node = n0 + r;
#pragma unroll
        for (int i = 0; i < 4; i++) {
            short8 s = {0, 0, 0, 0, 0, 0, 0, 0};
            if (node < N_NODES) {
                const float* ar = aggr + (size_t)node * HID + q * 32 + i * 8;
                float4 f0 = *(const float4*)ar;
                float4 f1 = *(const float4*)(ar + 4);
                s = (short8){bfb(f0.x), bfb(f0.y), bfb(f0.z), bfb(f0.w),
                             bfb(f1.x), bfb(f1.y), bfb(f1.z), bfb(f1.w)};
            }
            int cb = 128 + q * 64 + i * 16;
            *(short8*)((char*)at + r * 384 + (cb ^ ((r & 7) << 4))) = s;
        }
    }
    __syncthreads();

    f32x4 acc[4][2];
#pragma unroll
    for (int mi = 0; mi < 4; mi++)
#pragma unroll
        for (int ni = 0; ni < 2; ni++) acc[mi][ni] = (f32x4){0.f, 0.f, 0.f, 0.f};
#pragma unroll
    for (int ks = 0; ks < 6; ks++) {
        int kb = ks * 64 + lk * 16;
        short8 av[4];
#pragma unroll
        for (int mi = 0; mi < 4; mi++) {
            int row = mi * 16 + lrow;
            av[mi] = *(const short8*)((const char*)at + row * 384 + (kb ^ ((row & 7) << 4)));
        }
#pragma unroll
        for (int mi = 0; mi < 4; mi++)
#pragma unroll
            for (int ni = 0; ni < 2; ni++)
                acc[mi][ni] = __builtin_amdgcn_mfma_f32_16x16x32_bf16(av[mi], w1f[ks][ni], acc[mi][ni], 0, 0, 0);
    }
#pragma unroll
    for (int mi = 0; mi < 4; mi++) {
#pragma unroll
        for (int ni = 0; ni < 2; ni++) {
            int col = nc0 + ni * 16 + lrow;
#pragma unroll
            for (int rr = 0; rr < 4; rr++) {
                int row = mi * 16 + lk * 4 + rr;
                float val = sp_(acc[mi][ni][rr] + b1v[ni]);
                *(short*)((char*)ht + row * 256 + ((col * 2) ^ ((row & 7) << 4))) = bfb(val);
            }
        }
    }
    __syncthreads();

    f32x4 acc2[4];
#pragma unroll
    for (int mi = 0; mi < 4; mi++) acc2[mi] = (f32x4){0.f, 0.f, 0.f, 0.f};
#pragma unroll
    for (int ks = 0; ks < 4; ks++) {
        int kb = ks * 64 + lk * 16;
        short8 av[4];
#pragma unroll
        for (int mi = 0; mi < 4; mi++) {
            int row = mi * 16 + lrow;
            av[mi] = *(const short8*)((const char*)ht + row * 256 + (kb ^ ((row & 7) << 4)));
        }
#pragma unroll
        for (int mi = 0; mi < 4; mi++)
            acc2[mi] = __builtin_amdgcn_mfma_f32_16x16x32_bf16(av[mi], w2f[ks], acc2[mi], 0, 0, 0);
    }
    float s1 = 0.f, s2 = 0.f;
#pragma unroll
    for (int mi = 0; mi < 4; mi++) {
#pragma unroll
        for (int rr = 0; rr < 4; rr++) {
            int row = mi * 16 + lk * 4 + rr;
            int node = n0 + row;
            if (node < N_NODES) {
                float v = acc2[mi][rr] + b2v + xf[(size_t)node * DIM + col2];
                y[(size_t)node * DIM + col2] = v;
                s1 += v;
                s2 += v * v;
            }
        }
    }
    s1 += __shfl_xor(s1, 16); s1 += __shfl_xor(s1, 32);
    s2 += __shfl_xor(s2, 16); s2 += __shfl_xor(s2, 32);
    if (lane < 16) {
        atomicAdd(&stats[col2], s1);
        atomicAdd(&stats[64 + col2], s2);
    }
}

// ---------------------------------------------------------------- pool: per-graph mean + final BN (from raw stats)
__global__ void k_pool2(const int* __restrict__ gstart, const float* __restrict__ y,
                        const float* __restrict__ stats,
                        const float* __restrict__ gamma, const float* __restrict__ beta,
                        float* __restrict__ pooled) {
    __shared__ float red[256];
    const int g = blockIdx.x, t = threadIdx.x;
    const int d = t & 63, nl = t >> 6;
    const int s = gstart[g], e = gstart[g + 1];
    float sum = 0.f;
    for (int n = s + nl; n < e; n += 4)
        sum += y[(size_t)n * DIM + d];
    red[t] = sum;
    __syncthreads();
    if (t < 64) {
        float tot = red[t] + red[t + 64] + red[t + 128] + red[t + 192];
        int c = e - s;
        float mean = tot / fmaxf((float)c, 1.f);
        float mu = stats[t] * (1.f / N_NODES);
        float var = stats[64 + t] * (1.f / N_NODES) - mu * mu;
        float rstd = rsqrtf(var + BN_EPS);
        float a = gamma[t] * rstd;
        float b = beta[t] - mu * a;
        pooled[g * DIM + t] = a * mean + b;   // == mean(a*y+b)
    }
}

// ---------------------------------------------------------------- output MLP (f32)
__global__ void k_out(const float* __restrict__ pooled,
                      const float* __restrict__ W1, const float* __restrict__ b1,
                      const float* __restrict__ W2, const float* __restrict__ b2,
                      float* __restrict__ out) {
    __shared__ float pl[64];
    __shared__ float wsum[2];
    int g = blockIdx.x, t = threadIdx.x;
    if (t < 64) pl[t] = pooled[g * 64 + t];
    __syncthreads();
    float a = b1[t];
#pragma unroll
    for (int d = 0; d < 64; d++) a += pl[d] * W1[d * 128 + t];
    float c = sp_(a) * W2[t];
#pragma unroll
    for (int off = 32; off >= 1; off >>= 1) c += __shfl_down(c, off);
    int lane = t & 63, wid = t >> 6;
    if (lane == 0) wsum[wid] = c;
    __syncthreads();
    if (t == 0) out[g] = wsum[0] + wsum[1] + b2[0];
}

// ---------------------------------------------------------------- launch
extern "C" void kernel_launch(void* const* d_in, const int* in_sizes, int n_in,
                              void* d_out, int out_size, void* d_ws, size_t ws_size,
                              hipStream_t stream) {
    const int*   az    = (const int*)d_in[0];
    const int*   ei    = (const int*)d_in[1];
    const float* eattr = (const float*)d_in[2];
    const int*   batch = (const int*)d_in[3];
    const float* emb   = (const float*)d_in[4];
    const float* eW1   = (const float*)d_in[5];
    const float* eb1   = (const float*)d_in[6];
    const float* eW2   = (const float*)d_in[7];
    const float* eb2   = (const float*)d_in[8];
    const float* nW1   = (const float*)d_in[9];
    const float* nb1   = (const float*)d_in[10];
    const float* nW2   = (const float*)d_in[11];
    const float* nb2   = (const float*)d_in[12];
    const float* gam   = (const float*)d_in[13];
    const float* bet   = (const float*)d_in[14];
    const float* oW1   = (const float*)d_in[15];
    const float* ob1   = (const float*)d_in[16];
    const float* oW2   = (const float*)d_in[17];
    const float* ob2   = (const float*)d_in[18];
    const int* esrc = ei;
    const int* edst = ei + N_EDGES;

    float* x     = (float*)d_ws;
    float* y     = x + (size_t)N_NODES * DIM;
    float* aggr  = y + (size_t)N_NODES * DIM;
    float* stats = aggr + (size_t)N_NODES * HID;     // 256 floats (adjacent: joint memset)
    float* pooled = stats + 256;                     // [128][64]
    __hip_bfloat16* xb = (__hip_bfloat16*)(pooled + NGRAPH * DIM);
    short* ew1T = (short*)(xb + (size_t)N_NODES * DIM);   // [3][128][128]
    short* ew2T = ew1T + 3 * 128 * 128;                   // [3][128][128]
    short* nw1T = ew2T + 3 * 128 * 128;                   // [3][128][192]
    short* nw2T = nw1T + 3 * 128 * 192;                   // [3][64][128]
    int*   cursor = (int*)(nw2T + 3 * 64 * 128);          // [50000]
    int4v* sedge  = (int4v*)(cursor + N_NODES + 48);      // [800000] 16B recs (align)
    int*   gstart = (int*)(sedge + N_EDGES);              // [129]
    short* xab    = (short*)(gstart + 256);               // [50000][256] bf16

    k_embed<<<(N_NODES * DIM + 255) / 256, 256, 0, stream>>>(az, emb, x, xb);

    // pre-transpose all layer weights to bf16 [n][k]
    k_wprep<<<dim3(64, 3), 256, 0, stream>>>(eW1, ew1T, 128 * 128, 7, 129 * 128);
    k_wprep<<<dim3(64, 3), 256, 0, stream>>>(eW2, ew2T, 128 * 128, 7, 128 * 128);
    k_wprep<<<dim3(96, 3), 256, 0, stream>>>(nW1, nw1T, 192 * 128, 7, 192 * 128);
    k_wprep<<<dim3(32, 3), 256, 0, stream>>>(nW2, nw2T, 128 * 64, 6, 128 * 64);

    // counting sort of edges by dst (once per launch)
    hipMemsetAsync(cursor, 0, N_NODES * sizeof(int), stream);
    k_hist<<<(N_EDGES + 255) / 256, 256, 0, stream>>>(edst, cursor);
    k_scan<<<1, 1024, 0, stream>>>(cursor, cursor);   // in-place: per-thread own-index RMW
    k_scatter<<<(N_EDGES + 255) / 256, 256, 0, stream>>>(esrc, edst, eattr, cursor, sedge);
    k_gbounds<<<1, 256, 0, stream>>>(batch, gstart);

    for (int l = 0; l < 3; l++) {
        // A/B precompute (BN of previous layer fused in for l>=1).
        // NOTE: must run BEFORE the memset below (k_abF reads prev stats).
        if (l == 0)
            k_ab<<<(N_NODES + 63) / 64, 512, 0, stream>>>(xb, ew1T, eb1, xab);
        else
            k_abF<<<(N_NODES + 63) / 64, 512, 0, stream>>>(y, stats,
                                                           gam + (l - 1) * 64, bet + (l - 1) * 64,
                                                           ew1T + (size_t)l * 128 * 128, eb1 + l * 128,
                                                           x, xb, xab);
        hipMemsetAsync(aggr, 0, ((size_t)N_NODES * HID + 256) * sizeof(float), stream);
        k_edge<<<1000, 512, 0, stream>>>(xab, sedge,
                                         eW1 + (size_t)l * 129 * 128 + 128 * 128,
                                         eb2 + l * 128,
                                         ew2T + (size_t)l * 128 * 128,
                                         aggr);
        k_node<<<(N_NODES + 63) / 64, 256, 0, stream>>>(xb, x, aggr,
                                                        nw1T + (size_t)l * 128 * 192, nb1 + l * 128,
                                                        nw2T + (size_t)l * 64 * 128, nb2 + l * 64,
                                                        y, stats);
    }

    k_pool2<<<NGRAPH, 256, 0, stream>>>(gstart, y, stats, gam + 2 * 64, bet + 2 * 64, pooled);
    k_out<<<NGRAPH, 128, 0, stream>>>(pooled, oW1, ob1, oW2, ob2, (float*)d_out);
}

// Round 14
// 896.255 us; speedup vs baseline: 1.5327x; 1.0458x over previous
//
#include <hip/hip_runtime.h>
#include <hip/hip_bf16.h>

#define N_NODES 50000
#define N_EDGES 800000
#define DIM 64
#define HID 128
#define NGRAPH 128
#define BN_EPS 1e-5f

typedef __attribute__((ext_vector_type(8))) short short8;
typedef __attribute__((ext_vector_type(4))) short short4v;
typedef __attribute__((ext_vector_type(4))) float f32x4;
typedef __attribute__((ext_vector_type(4))) int int4v;

__device__ __forceinline__ float sp_(float v) {
    // softplus via hardware v_exp_f32 / v_log_f32 (~1e-6 abs err, fine at bf16)
    return fmaxf(v, 0.f) + __logf(1.f + __expf(-fabsf(v)));
}
__device__ __forceinline__ short bfb(float f) {
    __hip_bfloat16 h = __float2bfloat16(f);
    return __builtin_bit_cast(short, h);
}
__device__ __forceinline__ float b2f(short s) {
    unsigned u = ((unsigned)(unsigned short)s) << 16;
    return __builtin_bit_cast(float, u);
}

// ---------------------------------------------------------------- embed
__global__ void k_embed(const int* __restrict__ az, const float* __restrict__ emb,
                        float* __restrict__ x, __hip_bfloat16* __restrict__ xb) {
    int idx = blockIdx.x * 256 + threadIdx.x;
    if (idx >= N_NODES * DIM) return;
    int n = idx >> 6;
    int d = idx & 63;
    float v = emb[az[n] * DIM + d];
    x[idx] = v;
    xb[idx] = __float2bfloat16(v);
}

// ---------------------------------------------------------------- weight prep:
// transpose f32 [K][N] (row-major) -> bf16 [N][K]; blockIdx.y = layer
__global__ void k_wprep(const float* __restrict__ src, short* __restrict__ dst,
                        int total, int nshift, int srcStride) {
    int l = blockIdx.y;
    int idx = blockIdx.x * 256 + threadIdx.x;
    if (idx >= total) return;
    int K = total >> nshift;
    int k = idx >> nshift;
    int n = idx & ((1 << nshift) - 1);
    dst[(size_t)l * total + n * K + k] = bfb(src[(size_t)l * srcStride + idx]);
}

// ---------------------------------------------------------------- counting sort by dst
__global__ void k_hist(const int* __restrict__ edst, int* __restrict__ deg) {
    int e = blockIdx.x * 256 + threadIdx.x;
    if (e < N_EDGES) atomicAdd(&deg[edst[e]], 1);
}

// single block, 1024 threads: exclusive prefix sum deg -> cursor
__global__ void k_scan(const int* __restrict__ deg, int* __restrict__ cursor) {
    __shared__ int wsum[16];
    __shared__ int carry;
    const int t = threadIdx.x, lane = t & 63, w = t >> 6;
    if (t == 0) carry = 0;
    __syncthreads();
    for (int base = 0; base < N_NODES; base += 1024) {
        int i = base + t;
        int v = (i < N_NODES) ? deg[i] : 0;
        int s = v;
#pragma unroll
        for (int off = 1; off < 64; off <<= 1) {
            int u = __shfl_up(s, off);
            if (lane >= off) s += u;
        }
        if (lane == 63) wsum[w] = s;
        __syncthreads();
        if (w == 0) {
            int ws = (lane < 16) ? wsum[lane] : 0;
#pragma unroll
            for (int off = 1; off < 16; off <<= 1) {
                int u = __shfl_up(ws, off);
                if (lane >= off) ws += u;
            }
            if (lane < 16) wsum[lane] = ws;
        }
        __syncthreads();
        int woff = (w == 0) ? 0 : wsum[w - 1];
        int excl = carry + woff + s - v;
        if (i < N_NODES) cursor[i] = excl;
        __syncthreads();
        if (t == 1023) carry += wsum[15];
        __syncthreads();
    }
}

// scatter into interleaved edge records {src, dst, attr_bits, 0}
__global__ void k_scatter(const int* __restrict__ esrc, const int* __restrict__ edst,
                          const float* __restrict__ eattr, int* __restrict__ cursor,
                          int4v* __restrict__ sedge) {
    int e = blockIdx.x * 256 + threadIdx.x;
    if (e >= N_EDGES) return;
    int d = edst[e];
    int pos = atomicAdd(&cursor[d], 1);
    int4v rec = {esrc[e], d, __builtin_bit_cast(int, eattr[e]), 0};
    sedge[pos] = rec;
}

// ---------------------------------------------------------------- graph bounds
__global__ void k_gbounds(const int* __restrict__ batch, int* __restrict__ gstart) {
    int g = threadIdx.x;
    if (g > NGRAPH) return;
    int lo = 0, hi = N_NODES;
    while (lo < hi) {
        int mid = (lo + hi) >> 1;
        if (batch[mid] < g) lo = mid + 1; else hi = mid;
    }
    gstart[g] = lo;
}

// ---------------------------------------------------------------- per-node A/B (layer 0):
// A[n] = x[n]@W1[0:64] + b1, B[n] = x[n]@W1[64:128]
// output xab[n][0:128]=A bf16, [128:256]=B bf16; also zeroes this block's
// aggr slice (replaces the per-layer memset dispatch).
__launch_bounds__(512, 2)
__global__ void k_ab(const __hip_bfloat16* __restrict__ xb,
                     const short* __restrict__ w1T, const float* __restrict__ b1,
                     short* __restrict__ xab, float* __restrict__ aggr) {
    __shared__ short xt[64 * 64];     // 8KB, rowbytes 128
    __shared__ short ot[64 * 256];    // 32KB, rowbytes 512
    const int t = threadIdx.x;
    const int wid = t >> 6, lane = t & 63, lrow = lane & 15, lk = lane >> 4;
    const int col = wid * 16 + lrow;
    const int n0 = blockIdx.x * 64;

    // zero aggr[n0:n0+64][*] (overlaps with GEMM below)
    {
        float4 z4 = {0.f, 0.f, 0.f, 0.f};
#pragma unroll
        for (int i = 0; i < 4; i++) {
            int idx = (i * 512 + t) * 4;          // f32 offset in slice
            int node = n0 + (idx >> 7);
            if (node < N_NODES) *(float4*)(aggr + (size_t)n0 * HID + idx) = z4;
        }
    }

    short8 wa[2], wb[2];
#pragma unroll
    for (int ks = 0; ks < 2; ks++) {
        wa[ks] = *(const short8*)((const char*)w1T + col * 256 + ks * 64 + lk * 16);
        wb[ks] = *(const short8*)((const char*)w1T + col * 256 + 128 + ks * 64 + lk * 16);
    }
    const float b1v = b1[col];

    {   // stage x tile
        int r = t >> 3, q = t & 7;
        int node = n0 + r;
        int4v v = {0, 0, 0, 0};
        if (node < N_NODES) v = *(const int4v*)(xb + (size_t)node * DIM + q * 8);
        *(int4v*)((char*)xt + r * 128 + ((q * 16) ^ ((r & 7) << 4))) = v;
    }
    __syncthreads();

    f32x4 aa[4], ab[4];
#pragma unroll
    for (int mi = 0; mi < 4; mi++) { aa[mi] = (f32x4){0.f,0.f,0.f,0.f}; ab[mi] = (f32x4){0.f,0.f,0.f,0.f}; }
#pragma unroll
    for (int ks = 0; ks < 2; ks++) {
        int kb = ks * 64 + lk * 16;
        short8 av[4];
#pragma unroll
        for (int mi = 0; mi < 4; mi++) {
            int row = mi * 16 + lrow;
            av[mi] = *(const short8*)((const char*)xt + row * 128 + (kb ^ ((row & 7) << 4)));
        }
#pragma unroll
        for (int mi = 0; mi < 4; mi++) {
            aa[mi] = __builtin_amdgcn_mfma_f32_16x16x32_bf16(av[mi], wa[ks], aa[mi], 0, 0, 0);
            ab[mi] = __builtin_amdgcn_mfma_f32_16x16x32_bf16(av[mi], wb[ks], ab[mi], 0, 0, 0);
        }
    }
#pragma unroll
    for (int mi = 0; mi < 4; mi++) {
#pragma unroll
        for (int rr = 0; rr < 4; rr++) {
            int row = mi * 16 + lk * 4 + rr;
            int swz = (row & 7) << 4;
            *(short*)((char*)ot + row * 512 + ((col * 2) ^ swz)) = bfb(aa[mi][rr] + b1v);
            *(short*)((char*)ot + row * 512 + 256 + ((col * 2) ^ swz)) = bfb(ab[mi][rr]);
        }
    }
    __syncthreads();
    // coalesced LDS -> global copy (unswizzle)
#pragma unroll
    for (int it = 0; it < 4; it++) {
        int idx = it * 8192 + t * 16;
        int row = idx >> 9, off = idx & 511;
        int node = n0 + row;
        if (node < N_NODES) {
            int base = off & 256, lo = off & 255;
            int4v v = *(const int4v*)((char*)ot + row * 512 + base + (lo ^ ((row & 7) << 4)));
            *(int4v*)((char*)xab + (size_t)node * 512 + off) = v;
        }
    }
}

// ---------------------------------------------------------------- BN-fused A/B (layers 1,2):
// x = gamma*(y-mu)*rstd+beta (BN from raw stats), write x f32 + xb bf16,
// then A/B GEMM as k_ab. Also zeroes this block's aggr slice.
__launch_bounds__(512, 2)
__global__ void k_abF(const float* __restrict__ y,
                      const float* __restrict__ stats,
                      const float* __restrict__ gamma, const float* __restrict__ beta,
                      const short* __restrict__ w1T, const float* __restrict__ b1,
                      float* __restrict__ x, __hip_bfloat16* __restrict__ xb,
                      short* __restrict__ xab, float* __restrict__ aggr) {
    __shared__ short xt[64 * 64];     // 8KB
    __shared__ short ot[64 * 256];    // 32KB
    const int t = threadIdx.x;
    const int wid = t >> 6, lane = t & 63, lrow = lane & 15, lk = lane >> 4;
    const int col = wid * 16 + lrow;
    const int n0 = blockIdx.x * 64;

    // zero aggr[n0:n0+64][*]
    {
        float4 z4 = {0.f, 0.f, 0.f, 0.f};
#pragma unroll
        for (int i = 0; i < 4; i++) {
            int idx = (i * 512 + t) * 4;
            int node = n0 + (idx >> 7);
            if (node < N_NODES) *(float4*)(aggr + (size_t)n0 * HID + idx) = z4;
        }
    }

    short8 wa[2], wb[2];
#pragma unroll
    for (int ks = 0; ks < 2; ks++) {
        wa[ks] = *(const short8*)((const char*)w1T + col * 256 + ks * 64 + lk * 16);
        wb[ks] = *(const short8*)((const char*)w1T + col * 256 + 128 + ks * 64 + lk * 16);
    }
    const float b1v = b1[col];

    {   // stage: read y, BN affine, write x + xb + LDS bf16
        int r = t >> 3, q = t & 7;
        int node = n0 + r;
        short8 s = {0, 0, 0, 0, 0, 0, 0, 0};
        if (node < N_NODES) {
            const float* yr = y + (size_t)node * DIM + q * 8;
            float4 f0 = *(const float4*)yr;
            float4 f1 = *(const float4*)(yr + 4);
            float v[8] = {f0.x, f0.y, f0.z, f0.w, f1.x, f1.y, f1.z, f1.w};
            float o[8];
#pragma unroll
            for (int i = 0; i < 8; i++) {
                int d = q * 8 + i;
                float mu = stats[d] * (1.f / N_NODES);
                float var = stats[64 + d] * (1.f / N_NODES) - mu * mu;
                float rstd = rsqrtf(var + BN_EPS);
                float a = gamma[d] * rstd;
                float b = beta[d] - mu * a;
                o[i] = a * v[i] + b;
                s[i] = bfb(o[i]);
            }
            float4 g0 = {o[0], o[1], o[2], o[3]};
            float4 g1 = {o[4], o[5], o[6], o[7]};
            *(float4*)(x + (size_t)node * DIM + q * 8) = g0;
            *(float4*)(x + (size_t)node * DIM + q * 8 + 4) = g1;
            *(short8*)((char*)xb + ((size_t)node * DIM + q * 8) * 2) = s;
        }
        *(int4v*)((char*)xt + r * 128 + ((q * 16) ^ ((r & 7) << 4))) = __builtin_bit_cast(int4v, s);
    }
    __syncthreads();

    f32x4 aa[4], ab[4];
#pragma unroll
    for (int mi = 0; mi < 4; mi++) { aa[mi] = (f32x4){0.f,0.f,0.f,0.f}; ab[mi] = (f32x4){0.f,0.f,0.f,0.f}; }
#pragma unroll
    for (int ks = 0; ks < 2; ks++) {
        int kb = ks * 64 + lk * 16;
        short8 av[4];
#pragma unroll
        for (int mi = 0; mi < 4; mi++) {
            int row = mi * 16 + lrow;
            av[mi] = *(const short8*)((const char*)xt + row * 128 + (kb ^ ((row & 7) << 4)));
        }
#pragma unroll
        for (int mi = 0; mi < 4; mi++) {
            aa[mi] = __builtin_amdgcn_mfma_f32_16x16x32_bf16(av[mi], wa[ks], aa[mi], 0, 0, 0);
            ab[mi] = __builtin_amdgcn_mfma_f32_16x16x32_bf16(av[mi], wb[ks], ab[mi], 0, 0, 0);
        }
    }
#pragma unroll
    for (int mi = 0; mi < 4; mi++) {
#pragma unroll
        for (int rr = 0; rr < 4; rr++) {
            int row = mi * 16 + lk * 4 + rr;
            int swz = (row & 7) << 4;
            *(short*)((char*)ot + row * 512 + ((col * 2) ^ swz)) = bfb(aa[mi][rr] + b1v);
            *(short*)((char*)ot + row * 512 + 256 + ((col * 2) ^ swz)) = bfb(ab[mi][rr]);
        }
    }
    __syncthreads();
#pragma unroll
    for (int it = 0; it < 4; it++) {
        int idx = it * 8192 + t * 16;
        int row = idx >> 9, off = idx & 511;
        int node = n0 + row;
        if (node < N_NODES) {
            int base = off & 256, lo = off & 255;
            int4v v = *(const int4v*)((char*)ot + row * 512 + base + (lo ^ ((row & 7) << 4)));
            *(int4v*)((char*)xab + (size_t)node * 512 + off) = v;
        }
    }
}

// ---------------------------------------------------------------- edge MLP (dst-sorted, A/B precomputed)
// 2 barriers/tile; next-tile gathers prefetched under the reduce.
// Reduce: balanced per-row-group (16 rows/thread-group), flush atomics at
// segment/range ends via per-row dst (double-buffered so staging(t+1) can
// overwrite without a 3rd barrier). Block 0 also zeroes stats (for k_node).
// (512,4): VGPR cap 128; (512,6) spills (round 12 regression).
__launch_bounds__(512, 4)
__global__ void k_edge(const short* __restrict__ xab,
                       const int4v* __restrict__ sedge,
                       const float* __restrict__ wl, const float* __restrict__ b2,
                       const short* __restrict__ w2T,
                       float* __restrict__ aggr, float* __restrict__ stats) {
    __shared__ short ht[64 * 128];     // 16KB bf16 h-tile, rowbytes 256
    __shared__ float mt[64 * 128];     // 32KB f32 m-tile, rowbytes 512
    __shared__ int   dstb[2][64];      // per-row dst, double-buffered

    const int t = threadIdx.x;
    const int wid = t >> 6, lane = t & 63;
    const int lrow = lane & 15, lk = lane >> 4;
    const int r = t >> 3, q = t & 7;          // staging: 8 threads per edge row
    const int col = wid * 16 + lrow;          // GEMM output column

    if (blockIdx.x == 0 && t < 128) stats[t] = 0.f;   // replaces stats memset

    short8 w2f[4];
#pragma unroll
    for (int ks = 0; ks < 4; ks++)
        w2f[ks] = *(const short8*)((const char*)w2T + col * 256 + ks * 64 + lk * 16);
    const float b2v = b2[col];
    float wlv[16];
#pragma unroll
    for (int i = 0; i < 16; i++) wlv[i] = wl[q * 16 + i];

    const int NT = N_EDGES / 64;              // 12500
    const int tile0 = (int)(((long)blockIdx.x * NT) / 1000);
    const int tile1 = (int)(((long)(blockIdx.x + 1) * NT) / 1000);

    // ---- prefetch state (tile t+1 loads issued under tile t's reduce)
    int4v ei;
    short8 ra0, ra1, rb0, rb1;
    {
        int e = tile0 * 64 + r;
        ei = sedge[e];
        const char* pa = (const char*)xab + (size_t)ei[1] * 512 + q * 32;
        const char* pb = (const char*)xab + (size_t)ei[0] * 512 + 256 + q * 32;
        ra0 = *(const short8*)pa;  ra1 = *(const short8*)(pa + 16);
        rb0 = *(const short8*)pb;  rb1 = *(const short8*)(pb + 16);
    }

    for (int tile = tile0; tile < tile1; ++tile) {
        const int buf = tile & 1;
        // ---- stage h tile from prefetched regs: h = sp(A[dst]+B[src]+attr*wl)
        // safe pre-barrier: reduce(t-1) reads mt/dstb[1-buf] only
        {
            float at = __builtin_bit_cast(float, ei[2]);
            if (q == 0) dstb[buf][r] = ei[1];
            short8 h0, h1;
#pragma unroll
            for (int i = 0; i < 8; i++) {
                h0[i] = bfb(sp_(b2f(ra0[i]) + b2f(rb0[i]) + at * wlv[i]));
                h1[i] = bfb(sp_(b2f(ra1[i]) + b2f(rb1[i]) + at * wlv[8 + i]));
            }
            int swz = (r & 7) << 4;
            *(short8*)((char*)ht + r * 256 + ((q * 32) ^ swz)) = h0;
            *(short8*)((char*)ht + r * 256 + (((q * 32) + 16) ^ swz)) = h1;
        }
        __syncthreads();                       // A: ht + dstb[buf] ready (and all
                                               //    waves done with prev reduce)

        // ---- GEMM2: [64x128] @ [128x128], wave owns 16 cols
        f32x4 acc2[4];
#pragma unroll
        for (int mi = 0; mi < 4; mi++) acc2[mi] = (f32x4){0.f, 0.f, 0.f, 0.f};
#pragma unroll
        for (int ks = 0; ks < 4; ks++) {
            int kb = ks * 64 + lk * 16;
            short8 av[4];
#pragma unroll
            for (int mi = 0; mi < 4; mi++) {
                int row = mi * 16 + lrow;
                av[mi] = *(const short8*)((const char*)ht + row * 256 + (kb ^ ((row & 7) << 4)));
            }
#pragma unroll
            for (int mi = 0; mi < 4; mi++)
                acc2[mi] = __builtin_amdgcn_mfma_f32_16x16x32_bf16(av[mi], w2f[ks], acc2[mi], 0, 0, 0);
        }
        // epilogue: softplus(+b2) -> f32 m-tile
#pragma unroll
        for (int mi = 0; mi < 4; mi++) {
#pragma unroll
            for (int rr = 0; rr < 4; rr++) {
                int row = mi * 16 + lk * 4 + rr;
                *(float*)((char*)mt + row * 512 + ((col * 4) ^ ((row & 7) << 4))) = sp_(acc2[mi][rr] + b2v);
            }
        }
        __syncthreads();                       // C: m-tile visible

        // ---- prefetch next tile's gathers (latency hides under reduce)
        if (tile + 1 < tile1) {
            int e = (tile + 1) * 64 + r;
            ei = sedge[e];
            const char* pa = (const char*)xab + (size_t)ei[1] * 512 + q * 32;
            const char* pb = (const char*)xab + (size_t)ei[0] * 512 + 256 + q * 32;
            ra0 = *(const short8*)pa;  ra1 = *(const short8*)(pa + 16);
            rb0 = *(const short8*)pb;  rb1 = *(const short8*)(pb + 16);
        }

        // ---- balanced reduce: thread owns col (t&127), rows [g*16, g*16+16)
        {
            const int rcol = t & 127, g = t >> 7;
            const int r0 = g * 16;
            const int* ds = dstb[buf];
            float sum = 0.f;
#pragma unroll
            for (int rr = r0; rr < r0 + 16; rr++) {
                sum += *(const float*)((const char*)mt + rr * 512 + ((rcol * 4) ^ ((rr & 7) << 4)));
                bool flush = (rr == r0 + 15) || (ds[rr + 1] != ds[rr]);
                if (flush) {
                    atomicAdd(&aggr[(size_t)ds[rr] * HID + rcol], sum);
                    sum = 0.f;
                }
            }
        }
        // no barrier: next staging writes ht/dstb[1-buf] (not read by this
        // reduce); barrier A fences mt reuse collectively.
    }
}

// ---------------------------------------------------------------- node MLP + BN partial stats
__launch_bounds__(256, 3)
__global__ void k_node(const __hip_bfloat16* __restrict__ xb,
                       const float* __restrict__ xf,
                       const float* __restrict__ aggr,
                       const short* __restrict__ w1T, const float* __restrict__ b1,
                       const short* __restrict__ w2T, const float* __restrict__ b2,
                       float* __restrict__ y, float* __restrict__ stats) {
    __shared__ short at[64 * 192];    // 24KB rowbytes 384
    __shared__ short ht[64 * 128];    // 16KB

    const int t = threadIdx.x;
    const int wid = t >> 6, lane = t & 63, lrow = lane & 15, lk = lane >> 4;
    const int n0 = blockIdx.x * 64;

    const int nc0 = wid * 32;
    short8 w1f[6][2];
    float b1v[2];
#pragma unroll
    for (int ni = 0; ni < 2; ni++) {
        int col = nc0 + ni * 16 + lrow;
#pragma unroll
        for (int ks = 0; ks < 6; ks++) {
            int kb = ks * 64 + lk * 16;
            w1f[ks][ni] = *(const short8*)((const char*)w1T + col * 384 + kb);
        }
        b1v[ni] = b1[col];
    }
    const int nc2 = wid * 16;
    const int col2 = nc2 + lrow;
    short8 w2f[4];
#pragma unroll
    for (int ks = 0; ks < 4; ks++)
        w2f[ks] = *(const short8*)((const char*)w2T + col2 * 256 + ks * 64 + lk * 16);
    const float b2v = b2[col2];

    if (t < 64) {
        int node = n0 + t;
        if (node < N_NODES) {
            const __hip_bfloat16* xr = xb + (size_t)node * DIM;
#pragma unroll
            for (int i = 0; i < 8; i++) {
                int4v v = *(const int4v*)(xr + i * 8);
                *(int4v*)((char*)at + t * 384 + ((i * 16) ^ ((t & 7) << 4))) = v;
            }
        } else {
            int4v z = {0, 0, 0, 0};
#pragma unroll
            for (int i = 0; i < 8; i++)
                *(int4v*)((char*)at + t * 384 + ((i * 16) ^ ((t & 7) << 4))) = z;
        }
    }
    {
        int r = t >> 2, q = t & 3;
        int node = n0 + r;
#pragma unroll
        for (int i = 0; i < 4; i++) {
            short8 s = {0, 0, 0, 0, 0, 0, 0, 0};
            if (node < N_NODES) {
                const float* ar = aggr + (size_t)node * HID + q * 32 + i * 8;
                float4 f0 = *(const float4*)ar;
                float4 f1 = *(const float4*)(ar + 4);
                s = (short8){bfb(f0.x), bfb(f0.y), bfb(f0.z), bfb(f0.w),
                             bfb(f1.x), bfb(f1.y), bfb(f1.z), bfb(f1.w)};
            }
            int cb = 128 + q * 64 + i * 16;
            *(short8*)((char*)at + r * 384 + (cb ^ ((r & 7) << 4))) = s;
        }
    }
    __syncthreads();

    f32x4 acc[4][2];
#pragma unroll
    for (int mi = 0; mi < 4; mi++)
#pragma unroll
        for (int ni = 0; ni < 2; ni++) acc[mi][ni] = (f32x4){0.f, 0.f, 0.f, 0.f};
#pragma unroll
    for (int ks = 0; ks < 6; ks++) {
        int kb = ks * 64 + lk * 16;
        short8 av[4];
#pragma unroll
        for (int mi = 0; mi < 4; mi++) {
            int row = mi * 16 + lrow;
            av[mi] = *(const short8*)((const char*)at + row * 384 + (kb ^ ((row & 7) << 4)));
        }
#pragma unroll
        for (int mi = 0; mi < 4; mi++)
#pragma unroll
            for (int ni = 0; ni < 2; ni++)
                acc[mi][ni] = __builtin_amdgcn_mfma_f32_16x16x32_bf16(av[mi], w1f[ks][ni], acc[mi][ni], 0, 0, 0);
    }
#pragma unroll
    for (int mi = 0; mi < 4; mi++) {
#pragma unroll
        for (int ni = 0; ni < 2; ni++) {
            int col = nc0 + ni * 16 + lrow;
#pragma unroll
            for (int rr = 0; rr < 4; rr++) {
                int row = mi * 16 + lk * 4 + rr;
                float val = sp_(acc[mi][ni][rr] + b1v[ni]);
                *(short*)((char*)ht + row * 256 + ((col * 2) ^ ((row & 7) << 4))) = bfb(val);
            }
        }
    }
    __syncthreads();

    f32x4 acc2[4];
#pragma unroll
    for (int mi = 0; mi < 4; mi++) acc2[mi] = (f32x4){0.f, 0.f, 0.f, 0.f};
#pragma unroll
    for (int ks = 0; ks < 4; ks++) {
        int kb = ks * 64 + lk * 16;
        short8 av[4];
#pragma unroll
        for (int mi = 0; mi < 4; mi++) {
            int row = mi * 16 + lrow;
            av[mi] = *(const short8*)((const char*)ht + row * 256 + (kb ^ ((row & 7) << 4)));
        }
#pragma unroll
        for (int mi = 0; mi < 4; mi++)
            acc2[mi] = __builtin_amdgcn_mfma_f32_16x16x32_bf16(av[mi], w2f[ks], acc2[mi], 0, 0, 0);
    }
    float s1 = 0.f, s2 = 0.f;
#pragma unroll
    for (int mi = 0; mi < 4; mi++) {
#pragma unroll
        for (int rr = 0; rr < 4; rr++) {
            int row = mi * 16 + lk * 4 + rr;
            int node = n0 + row;
            if (node < N_NODES) {
                float v = acc2[mi][rr] + b2v + xf[(size_t)node * DIM + col2];
                y[(size_t)node * DIM + col2] = v;
                s1 += v;
                s2 += v * v;
            }
        }
    }
    s1 += __shfl_xor(s1, 16); s1 += __shfl_xor(s1, 32);
    s2 += __shfl_xor(s2, 16); s2 += __shfl_xor(s2, 32);
    if (lane < 16) {
        atomicAdd(&stats[col2], s1);
        atomicAdd(&stats[64 + col2], s2);
    }
}

// ---------------------------------------------------------------- pool: per-graph mean + final BN (from raw stats)
__global__ void k_pool2(const int* __restrict__ gstart, const float* __restrict__ y,
                        const float* __restrict__ stats,
                        const float* __restrict__ gamma, const float* __restrict__ beta,
                        float* __restrict__ pooled) {
    __shared__ float red[256];
    const int g = blockIdx.x, t = threadIdx.x;
    const int d = t & 63, nl = t >> 6;
    const int s = gstart[g], e = gstart[g + 1];
    float sum = 0.f;
    for (int n = s + nl; n < e; n += 4)
        sum += y[(size_t)n * DIM + d];
    red[t] = sum;
    __syncthreads();
    if (t < 64) {
        float tot = red[t] + red[t + 64] + red[t + 128] + red[t + 192];
        int c = e - s;
        float mean = tot / fmaxf((float)c, 1.f);
        float mu = stats[t] * (1.f / N_NODES);
        float var = stats[64 + t] * (1.f / N_NODES) - mu * mu;
        float rstd = rsqrtf(var + BN_EPS);
        float a = gamma[t] * rstd;
        float b = beta[t] - mu * a;
        pooled[g * DIM + t] = a * mean + b;   // == mean(a*y+b)
    }
}

// ---------------------------------------------------------------- output MLP (f32)
__global__ void k_out(const float* __restrict__ pooled,
                      const float* __restrict__ W1, const float* __restrict__ b1,
                      const float* __restrict__ W2, const float* __restrict__ b2,
                      float* __restrict__ out) {
    __shared__ float pl[64];
    __shared__ float wsum[2];
    int g = blockIdx.x, t = threadIdx.x;
    if (t < 64) pl[t] = pooled[g * 64 + t];
    __syncthreads();
    float a = b1[t];
#pragma unroll
    for (int d = 0; d < 64; d++) a += pl[d] * W1[d * 128 + t];
    float c = sp_(a) * W2[t];
#pragma unroll
    for (int off = 32; off >= 1; off >>= 1) c += __shfl_down(c, off);
    int lane = t & 63, wid = t >> 6;
    if (lane == 0) wsum[wid] = c;
    __syncthreads();
    if (t == 0) out[g] = wsum[0] + wsum[1] + b2[0];
}

// ---------------------------------------------------------------- launch
extern "C" void kernel_launch(void* const* d_in, const int* in_sizes, int n_in,
                              void* d_out, int out_size, void* d_ws, size_t ws_size,
                              hipStream_t stream) {
    const int*   az    = (const int*)d_in[0];
    const int*   ei    = (const int*)d_in[1];
    const float* eattr = (const float*)d_in[2];
    const int*   batch = (const int*)d_in[3];
    const float* emb   = (const float*)d_in[4];
    const float* eW1   = (const float*)d_in[5];
    const float* eb1   = (const float*)d_in[6];
    const float* eW2   = (const float*)d_in[7];
    const float* eb2   = (const float*)d_in[8];
    const float* nW1   = (const float*)d_in[9];
    const float* nb1   = (const float*)d_in[10];
    const float* nW2   = (const float*)d_in[11];
    const float* nb2   = (const float*)d_in[12];
    const float* gam   = (const float*)d_in[13];
    const float* bet   = (const float*)d_in[14];
    const float* oW1   = (const float*)d_in[15];
    const float* ob1   = (const float*)d_in[16];
    const float* oW2   = (const float*)d_in[17];
    const float* ob2   = (const float*)d_in[18];
    const int* esrc = ei;
    const int* edst = ei + N_EDGES;

    float* x     = (float*)d_ws;
    float* y     = x + (size_t)N_NODES * DIM;
    float* aggr  = y + (size_t)N_NODES * DIM;
    float* stats = aggr + (size_t)N_NODES * HID;
    float* pooled = stats + 256;                     // [128][64]
    __hip_bfloat16* xb = (__hip_bfloat16*)(pooled + NGRAPH * DIM);
    short* ew1T = (short*)(xb + (size_t)N_NODES * DIM);   // [3][128][128]
    short* ew2T = ew1T + 3 * 128 * 128;                   // [3][128][128]
    short* nw1T = ew2T + 3 * 128 * 128;                   // [3][128][192]
    short* nw2T = nw1T + 3 * 128 * 192;                   // [3][64][128]
    int*   cursor = (int*)(nw2T + 3 * 64 * 128);          // [50000]
    int4v* sedge  = (int4v*)(cursor + N_NODES + 48);      // [800000] 16B recs (align)
    int*   gstart = (int*)(sedge + N_EDGES);              // [129]
    short* xab    = (short*)(gstart + 256);               // [50000][256] bf16

    k_embed<<<(N_NODES * DIM + 255) / 256, 256, 0, stream>>>(az, emb, x, xb);

    // pre-transpose all layer weights to bf16 [n][k]
    k_wprep<<<dim3(64, 3), 256, 0, stream>>>(eW1, ew1T, 128 * 128, 7, 129 * 128);
    k_wprep<<<dim3(64, 3), 256, 0, stream>>>(eW2, ew2T, 128 * 128, 7, 128 * 128);
    k_wprep<<<dim3(96, 3), 256, 0, stream>>>(nW1, nw1T, 192 * 128, 7, 192 * 128);
    k_wprep<<<dim3(32, 3), 256, 0, stream>>>(nW2, nw2T, 128 * 64, 6, 128 * 64);

    // counting sort of edges by dst (once per launch)
    hipMemsetAsync(cursor, 0, N_NODES * sizeof(int), stream);
    k_hist<<<(N_EDGES + 255) / 256, 256, 0, stream>>>(edst, cursor);
    k_scan<<<1, 1024, 0, stream>>>(cursor, cursor);   // in-place: per-thread own-index RMW
    k_scatter<<<(N_EDGES + 255) / 256, 256, 0, stream>>>(esrc, edst, eattr, cursor, sedge);
    k_gbounds<<<1, 256, 0, stream>>>(batch, gstart);

    for (int l = 0; l < 3; l++) {
        // A/B precompute (BN of previous layer fused for l>=1) + aggr zeroing.
        if (l == 0)
            k_ab<<<(N_NODES + 63) / 64, 512, 0, stream>>>(xb, ew1T, eb1, xab, aggr);
        else
            k_abF<<<(N_NODES + 63) / 64, 512, 0, stream>>>(y, stats,
                                                           gam + (l - 1) * 64, bet + (l - 1) * 64,
                                                           ew1T + (size_t)l * 128 * 128, eb1 + l * 128,
                                                           x, xb, xab, aggr);
        // k_edge block 0 zeroes stats (consumed by k_node after k_edge).
        k_edge<<<1000, 512, 0, stream>>>(xab, sedge,
                                         eW1 + (size_t)l * 129 * 128 + 128 * 128,
                                         eb2 + l * 128,
                                         ew2T + (size_t)l * 128 * 128,
                                         aggr, stats);
        k_node<<<(N_NODES + 63) / 64, 256, 0, stream>>>(xb, x, aggr,
                                                        nw1T + (size_t)l * 128 * 192, nb1 + l * 128,
                                                        nw2T + (size_t)l * 64 * 128, nb2 + l * 64,
                                                        y, stats);
    }

    k_pool2<<<NGRAPH, 256, 0, stream>>>(gstart, y, stats, gam + 2 * 64, bet + 2 * 64, pooled);
    k_out<<<NGRAPH, 128, 0, stream>>>(pooled, oW1, ob1, oW2, ob2, (float*)d_out);
}